// Round 9
// baseline (275.294 us; speedup 1.0000x reference)
//
#include <hip/hip_runtime.h>

#define OUT_F 11008
#define IN_F  4096
#define NBATCH 8
#define R 4                       // rows per block
#define BLOCK 256
#define COLS 1024                 // cols per block (chunk)
#define CHUNKS (IN_F / COLS)      // 4
#define NGR 32                    // groups per row
#define GPC (COLS / 128)          // 8 groups per chunk

// No k-loop. VMEM queue = pure idx stream (x and lut staged in LDS ->
// lgkmcnt domain, decoupled from the in-order vmcnt queue that was
// draining the idx prefetch in R6-R8). One barrier, then all-register FMAs.
__global__ __launch_bounds__(BLOCK) void pal_linear_kernel(
    const float* __restrict__ x,        // [8, 4096]
    const int*   __restrict__ widx,     // [11008*4096] in [0,16)
    const float* __restrict__ lut,      // [352256, 16] f32 on device
    const float* __restrict__ bias,     // [11008]
    float* __restrict__ out)            // [8, 11008], zeroed by memsetAsync
{
    __shared__ float xS[NBATCH * COLS];        // 32 KB
    __shared__ float lutS[R * GPC * 16];       // 2 KB
    __shared__ float red[BLOCK / 64][32];      // 512 B

    const int tid   = threadIdx.x;
    const int lane  = tid & 63;
    const int wave  = tid >> 6;                // col segment 0..3 within chunk
    const int rowG  = blockIdx.x >> 2;
    const int chunk = blockIdx.x & 3;
    const int o0    = rowG * R;
    const int c0    = chunk * COLS;
    const int cl    = c0 + wave * 256 + 4 * lane;   // lane's first col

    // ---- 1) idx loads FIRST: oldest in the vmcnt queue, 4KB/wave in flight ----
    int4 idx[R];
#pragma unroll
    for (int r = 0; r < R; ++r)
        idx[r] = *reinterpret_cast<const int4*>(
            widx + (size_t)(o0 + r) * IN_F + cl);

    // ---- 2) stage x chunk (L2-hot, 32KB) into LDS ----
#pragma unroll
    for (int m = 0; m < NBATCH; ++m)
        reinterpret_cast<float4*>(xS)[m * (COLS / 4) + tid] =
            *reinterpret_cast<const float4*>(x + m * IN_F + c0 + 4 * tid);

    // ---- 3) stage lut slice: R rows x 8 groups x 16 = 512 floats ----
    if (tid < 128) {
        const int r = tid >> 5;
        const int q = tid & 31;
        reinterpret_cast<float4*>(lutS)[tid] =
            *reinterpret_cast<const float4*>(
                lut + ((size_t)(o0 + r) * NGR + chunk * GPC) * 16 + 4 * q);
    }

    __syncthreads();

    // ---- 4) gathers from LDS: bank-conflict-free (16 idx -> 16 distinct banks,
    //         equal idx -> broadcast); lo/hi half-waves use disjoint bank halves
    const int gb = (wave * 2 + (lane >> 5)) * 16;
    float w[R][4];
#pragma unroll
    for (int r = 0; r < R; ++r) {
        const float* lr = lutS + r * (GPC * 16) + gb;
        w[r][0] = lr[idx[r].x];
        w[r][1] = lr[idx[r].y];
        w[r][2] = lr[idx[r].z];
        w[r][3] = lr[idx[r].w];
    }

    // ---- 5) FMAs: x from LDS (lgkmcnt), all static indexing ----
    float acc[R][NBATCH];
    const int xoff = wave * 256 + 4 * lane;
#pragma unroll
    for (int m = 0; m < NBATCH; ++m) {
        const float4 xv = *reinterpret_cast<const float4*>(xS + m * COLS + xoff);
#pragma unroll
        for (int r = 0; r < R; ++r) {
            float a = w[r][0] * xv.x;
            a = fmaf(w[r][1], xv.y, a);
            a = fmaf(w[r][2], xv.z, a);
            a = fmaf(w[r][3], xv.w, a);
            acc[r][m] = a;
        }
    }

    // ---- 6) wave reduction (R8-verified): fold halves, pack even/odd m ----
    float f[R][NBATCH];
#pragma unroll
    for (int r = 0; r < R; ++r)
#pragma unroll
        for (int m = 0; m < NBATCH; ++m)
            f[r][m] = acc[r][m] + __shfl_xor(acc[r][m], 32, 64);
    float e[16];
#pragma unroll
    for (int r = 0; r < R; ++r)
#pragma unroll
        for (int q = 0; q < 4; ++q)
            e[r * 4 + q] = (lane < 32) ? f[r][2 * q] : f[r][2 * q + 1];
#pragma unroll
    for (int off = 16; off >= 1; off >>= 1)
#pragma unroll
        for (int p = 0; p < 16; ++p)
            e[p] += __shfl_xor(e[p], off, 64);

    // writers: lanes 0-15 (even m), lanes 32-47 (odd m); static select (R5 lesson)
    const int p = lane & 15;
    float v = 0.0f;
#pragma unroll
    for (int pp = 0; pp < 16; ++pp)
        if (p == pp) v = e[pp];

    const bool lo = (lane < 16);
    const bool hi = (lane >= 32) && (lane < 48);
    if (lo || hi) red[wave][(lo ? 0 : 16) + p] = v;
    __syncthreads();

    // ---- 7) cross-wave combine + one atomicAdd per (r,m) per block ----
    if (tid < 32) {
        float t = red[0][tid] + red[1][tid] + red[2][tid] + red[3][tid];
        const int half = tid >> 4;            // 0: even m, 1: odd m
        const int pp   = tid & 15;
        const int r    = pp >> 2;
        const int m    = 2 * (pp & 3) + half;
        const int row  = o0 + r;
        if (chunk == 0) t += bias[row];       // bias exactly once per (row,m)
        atomicAdd(out + (size_t)m * OUT_F + row, t);
    }
}

extern "C" void kernel_launch(void* const* d_in, const int* in_sizes, int n_in,
                              void* d_out, int out_size, void* d_ws, size_t ws_size,
                              hipStream_t stream) {
    const float* x    = (const float*)d_in[0];
    const int*   widx = (const int*)d_in[1];
    const float* lut  = (const float*)d_in[2];
    const float* bias = (const float*)d_in[3];
    float* out = (float*)d_out;

    hipMemsetAsync(out, 0, (size_t)out_size * sizeof(float), stream);
    pal_linear_kernel<<<(OUT_F / R) * CHUNKS, BLOCK, 0, stream>>>(
        x, widx, lut, bias, out);
}